// Round 1
// baseline (323.460 us; speedup 1.0000x reference)
//
#include <hip/hip_runtime.h>
#include <hip/hip_bf16.h>

typedef unsigned short u16;
typedef __attribute__((ext_vector_type(8))) short bf16x8;
typedef __attribute__((ext_vector_type(4))) float f32x4;
typedef __attribute__((address_space(3))) unsigned lds_u32;
typedef const __attribute__((address_space(1))) unsigned glb_u32;

#define N 256
#define D 128
#define NH 4
#define KD 32
#define NN 65536
#define QK_SCALE 0.17677669529663687f
#define HUGE_MASK 32768.0f

__device__ __forceinline__ float b2f(u16 s) {
  union { float f; unsigned u; } x; x.u = ((unsigned)s) << 16; return x.f;
}
__device__ __forceinline__ u16 f2b(float f) {
  union { float f; unsigned u; } x; x.f = f;
  unsigned r = x.u + 0x7fff + ((x.u >> 16) & 1);
  return (u16)(r >> 16);
}

// ---- Kernel 0: convert 5 weight mats fp32 -> bf16 into the swizzled LDS
// image layout: wb[mat][row*128 + gp*8 + j] = bf16(W[row][g*8+j]),
// gp = (g + (row&15)) & 15. One 8-elem group per thread.
__global__ __launch_bounds__(256) void prep_w_kernel(
    const float* __restrict__ wq, const float* __restrict__ wk,
    const float* __restrict__ wv, const float* __restrict__ wg,
    const float* __restrict__ wo, u16* __restrict__ wb)
{
  int idx = blockIdx.x * 256 + threadIdx.x;          // 0 .. 10239
  const float* srcs[5] = {wq, wk, wv, wg, wo};
  int mat = idx >> 11, rem = idx & 2047;
  int row = rem >> 4, g = rem & 15;
  int gp = (g + (row & 15)) & 15;
  const float* s = srcs[mat] + row * 128 + g * 8;
  float4 f0 = *(const float4*)(s);
  float4 f1 = *(const float4*)(s + 4);
  uint4 pk;
  pk.x = (unsigned)f2b(f0.x) | ((unsigned)f2b(f0.y) << 16);
  pk.y = (unsigned)f2b(f0.z) | ((unsigned)f2b(f0.w) << 16);
  pk.z = (unsigned)f2b(f1.x) | ((unsigned)f2b(f1.y) << 16);
  pk.w = (unsigned)f2b(f1.z) | ((unsigned)f2b(f1.w) << 16);
  *(uint4*)(wb + (size_t)mat * 16384 + row * 128 + gp * 8) = pk;
}

// Async-stage 32 KB (one swizzled weight mat) global -> LDS, width 16.
// LDS dest is wave-uniform base + lane*16 (HW rule), so copy is linear.
__device__ __forceinline__ void async_stage(const u16* __restrict__ gsrc, u16* lds, int tid) {
  int lane = tid & 63, wave = tid >> 6;
  u16* lbase = lds + wave * 512;                 // 1 KB per wave per pass
  const u16* gbase = gsrc + wave * 512 + lane * 8;
#pragma unroll
  for (int p = 0; p < 8; p++) {
    __builtin_amdgcn_global_load_lds((glb_u32*)(gbase + p * 2048),
                                     (lds_u32*)(lbase + p * 2048), 16, 0, 0);
  }
}

// ---------------- Kernel 1: fused LN + nb + q,k,v,g projections --------------
// Grid 512 x 256thr. M=128 rows/block, 2 m-tiles/wave. Weights double-buffered
// via global_load_lds from pre-swizzled wb. nb stored NATURAL order [h][i][j].
__global__ __launch_bounds__(256) void projln_kernel(
    const float* __restrict__ pa, const float* __restrict__ lns, const float* __restrict__ lnb,
    const float* __restrict__ w2d, const u16* __restrict__ wb, const float* __restrict__ bg,
    u16* __restrict__ q, u16* __restrict__ k, u16* __restrict__ v, u16* __restrict__ g,
    float* __restrict__ nb)
{
  __shared__ __align__(16) u16 Wl[2][16384];
  int tid = threadIdx.x;
  int wave = tid >> 6, lane = tid & 63;
  int lr = lane & 15, quad = lane >> 4;

  async_stage(wb, Wl[0], tid);   // mat 0 in flight while LN runs

  bf16x8 a[2][4];
#pragma unroll
  for (int mt = 0; mt < 2; mt++) {
    int row = blockIdx.x * 128 + wave * 32 + mt * 16 + lr;
    const float* rp = pa + (size_t)row * D;
    float xv[4][8];
    float s = 0.f, ss = 0.f;
#pragma unroll
    for (int ks = 0; ks < 4; ks++) {
      float4 a0 = *(const float4*)(rp + ks * 32 + quad * 8);
      float4 a1 = *(const float4*)(rp + ks * 32 + quad * 8 + 4);
      xv[ks][0] = a0.x; xv[ks][1] = a0.y; xv[ks][2] = a0.z; xv[ks][3] = a0.w;
      xv[ks][4] = a1.x; xv[ks][5] = a1.y; xv[ks][6] = a1.z; xv[ks][7] = a1.w;
#pragma unroll
      for (int j = 0; j < 8; j++) { s += xv[ks][j]; ss += xv[ks][j] * xv[ks][j]; }
    }
    s  += __shfl_xor(s, 16, 64);  ss += __shfl_xor(ss, 16, 64);
    s  += __shfl_xor(s, 32, 64);  ss += __shfl_xor(ss, 32, 64);
    float mu = s * (1.0f / D);
    float var = ss * (1.0f / D) - mu * mu;
    float rs = rsqrtf(var + 1e-5f);
#pragma unroll
    for (int ks = 0; ks < 4; ks++) {
      float4 s0 = *(const float4*)(lns + ks * 32 + quad * 8);
      float4 s1 = *(const float4*)(lns + ks * 32 + quad * 8 + 4);
      float4 b0 = *(const float4*)(lnb + ks * 32 + quad * 8);
      float4 b1 = *(const float4*)(lnb + ks * 32 + quad * 8 + 4);
      float sc[8] = {s0.x,s0.y,s0.z,s0.w,s1.x,s1.y,s1.z,s1.w};
      float bi[8] = {b0.x,b0.y,b0.z,b0.w,b1.x,b1.y,b1.z,b1.w};
#pragma unroll
      for (int j = 0; j < 8; j++) xv[ks][j] = (xv[ks][j] - mu) * rs * sc[j] + bi[j];
    }
#pragma unroll
    for (int h = 0; h < NH; h++) {
      float p = 0.f;
#pragma unroll
      for (int ks = 0; ks < 4; ks++) {
        float4 w0 = *(const float4*)(w2d + h * D + ks * 32 + quad * 8);
        float4 w1 = *(const float4*)(w2d + h * D + ks * 32 + quad * 8 + 4);
        p += xv[ks][0]*w0.x + xv[ks][1]*w0.y + xv[ks][2]*w0.z + xv[ks][3]*w0.w
           + xv[ks][4]*w1.x + xv[ks][5]*w1.y + xv[ks][6]*w1.z + xv[ks][7]*w1.w;
      }
      p += __shfl_xor(p, 16, 64);
      p += __shfl_xor(p, 32, 64);
      if (quad == 0)
        nb[(size_t)h * NN + row] = p;   // natural [h][i][j] order, coalesced
    }
#pragma unroll
    for (int ks = 0; ks < 4; ks++)
#pragma unroll
      for (int j = 0; j < 8; j++) a[mt][ks][j] = (short)f2b(xv[ks][j]);
  }
  __syncthreads();   // drains mat-0 global_load_lds (vmcnt) + all waves ready

  u16* Os[4] = {q, k, v, g};
#pragma unroll
  for (int mat = 0; mat < 4; mat++) {
    if (mat < 3) async_stage(wb + (size_t)(mat + 1) * 16384, Wl[(mat + 1) & 1], tid);
    const u16* Wcur = Wl[mat & 1];
    f32x4 acc[2][2][4];
#pragma unroll
    for (int mt = 0; mt < 2; mt++)
#pragma unroll
      for (int tg = 0; tg < 2; tg++)
#pragma unroll
        for (int e = 0; e < 4; e++) acc[mt][tg][e] = (f32x4){0.f, 0.f, 0.f, 0.f};
#pragma unroll
    for (int ks = 0; ks < 4; ks++) {
#pragma unroll
      for (int tg = 0; tg < 2; tg++) {
#pragma unroll
        for (int e = 0; e < 4; e++) {
          int nrow = tg * 64 + 4 * lr + e;
          int gp = (ks * 4 + quad + (nrow & 15)) & 15;
          bf16x8 b = *(const bf16x8*)(&Wcur[nrow * 128 + gp * 8]);
          acc[0][tg][e] = __builtin_amdgcn_mfma_f32_16x16x32_bf16(a[0][ks], b, acc[0][tg][e], 0, 0, 0);
          acc[1][tg][e] = __builtin_amdgcn_mfma_f32_16x16x32_bf16(a[1][ks], b, acc[1][tg][e], 0, 0, 0);
        }
      }
    }
    u16* O = Os[mat];
#pragma unroll
    for (int mt = 0; mt < 2; mt++) {
      int row0 = blockIdx.x * 128 + wave * 32 + mt * 16 + quad * 4;
#pragma unroll
      for (int tg = 0; tg < 2; tg++) {
        int c0 = tg * 64 + 4 * lr;
        float bg0 = 0.f, bg1 = 0.f, bg2 = 0.f, bg3 = 0.f;
        if (mat == 3) { bg0 = bg[c0]; bg1 = bg[c0+1]; bg2 = bg[c0+2]; bg3 = bg[c0+3]; }
#pragma unroll
        for (int reg = 0; reg < 4; reg++) {
          float v0 = acc[mt][tg][0][reg], v1 = acc[mt][tg][1][reg];
          float v2 = acc[mt][tg][2][reg], v3 = acc[mt][tg][3][reg];
          if (mat == 0) { v0 *= QK_SCALE; v1 *= QK_SCALE; v2 *= QK_SCALE; v3 *= QK_SCALE; }
          if (mat == 3) {
            v0 = 1.0f / (1.0f + __expf(-(v0 + bg0)));
            v1 = 1.0f / (1.0f + __expf(-(v1 + bg1)));
            v2 = 1.0f / (1.0f + __expf(-(v2 + bg2)));
            v3 = 1.0f / (1.0f + __expf(-(v3 + bg3)));
          }
          uint2 pk;
          pk.x = (unsigned)f2b(v0) | ((unsigned)f2b(v1) << 16);
          pk.y = (unsigned)f2b(v2) | ((unsigned)f2b(v3) << 16);
          *(uint2*)(O + (size_t)(row0 + reg) * D + c0) = pk;
        }
      }
    }
    __syncthreads();   // next buffer staged (vmcnt drained) + reads done
  }
}

// ---------------- Kernel 2: attention per (r, h) — in-register P path --------
// QK^T computed OPERAND-SWAPPED: S_t = mfma(K_frag, Q_frag) so lane (quad,lr)
// holds S[i = i0+lr][j = 16t + 4*quad + reg]  (one full query row per lane).
// Softmax is per-lane + 2 shfl_xor. P never touches LDS: the lane's own 8
// exp() values per 32-j chunk ARE the PV A-fragment under the k-slot
// permutation pi(8q+jj) = (jj<4 ? 4q+jj : 16+4q+jj-4), which is applied to
// V's LDS staging scatter instead (contraction is permutation-invariant).
__global__ __launch_bounds__(256, 4) void attn_kernel(
    const u16* __restrict__ q, const u16* __restrict__ k, const u16* __restrict__ v,
    const u16* __restrict__ g, const float* __restrict__ nb, const float* __restrict__ mask,
    u16* __restrict__ og)
{
  __shared__ __align__(16) u16 Kf[8192];
  __shared__ __align__(16) u16 Vf[8192];
  __shared__ float bias_lds[256];
  int h = blockIdx.x & 3, r = blockIdx.x >> 2;
  int tid = threadIdx.x;
  {
    int j = tid;
    const u16* krow = k + ((size_t)r * N + j) * D + h * KD;
    int t = j >> 4, lrj = j & 15;
#pragma unroll
    for (int qc = 0; qc < 4; qc++)
      *(bf16x8*)(&Kf[((t * 4 + qc) * 16 + lrj) * 8]) = *(const bf16x8*)(krow + qc * 8);
    const u16* vrow = v + ((size_t)r * N + j) * D + h * KD;
    // inverse of pi: source j-rel -> (quad qv, elem jv) slot in the B-fragment
    int ksrc = j >> 5, jrel = j & 31;
    int qv, jv;
    if (jrel < 16) { qv = jrel >> 2; jv = jrel & 3; }
    else           { qv = (jrel & 15) >> 2; jv = 4 + (jrel & 3); }
#pragma unroll
    for (int c = 0; c < 32; c++)
      Vf[(((ksrc * 2 + (c & 1)) * 4 + qv) * 16 + (c >> 1)) * 8 + jv] = vrow[c];
    bias_lds[tid] = HUGE_MASK * (mask[r * N + tid] - 1.0f);
  }
  __syncthreads();
  int wave = tid >> 6, lane = tid & 63;
  int lr = lane & 15, quad = lane >> 4;
  const float* nbh = nb + (size_t)h * NN;

  for (int pass = 0; pass < 4; pass++) {
    int i0 = pass * 64 + wave * 16;
    int irow = i0 + lr;
    bf16x8 af = *(const bf16x8*)(q + ((size_t)r * N + irow) * D + h * KD + quad * 8);
    f32x4 S[16];
#pragma unroll
    for (int t = 0; t < 16; t++) {
      bf16x8 kfr = *(const bf16x8*)(&Kf[((t * 4 + quad) * 16 + lr) * 8]);
      S[t] = __builtin_amdgcn_mfma_f32_16x16x32_bf16(kfr, af, (f32x4){0.f,0.f,0.f,0.f}, 0, 0, 0);
    }
    // add nb[h][irow][j] + mask bias(j); all 64 values belong to row irow
    float mx0 = -3e38f, mx1 = -3e38f, mx2 = -3e38f, mx3 = -3e38f;
    const float* nbrow = nbh + (size_t)irow * N;
#pragma unroll
    for (int t = 0; t < 16; t++) {
      int jb = t * 16 + quad * 4;
      float4 nb4 = *(const float4*)(nbrow + jb);
      float4 b4  = *(const float4*)(&bias_lds[jb]);
      S[t][0] += nb4.x + b4.x;  S[t][1] += nb4.y + b4.y;
      S[t][2] += nb4.z + b4.z;  S[t][3] += nb4.w + b4.w;
      mx0 = fmaxf(mx0, S[t][0]); mx1 = fmaxf(mx1, S[t][1]);
      mx2 = fmaxf(mx2, S[t][2]); mx3 = fmaxf(mx3, S[t][3]);
    }
    float mx = fmaxf(fmaxf(mx0, mx1), fmaxf(mx2, mx3));
    mx = fmaxf(mx, __shfl_xor(mx, 16, 64));   // cross-quad: full row max
    mx = fmaxf(mx, __shfl_xor(mx, 32, 64));
    float ls0 = 0.f, ls1 = 0.f;
    unsigned pw[32];
#pragma unroll
    for (int t = 0; t < 16; t++) {
      float p0 = __expf(S[t][0] - mx);
      float p1 = __expf(S[t][1] - mx);
      float p2 = __expf(S[t][2] - mx);
      float p3 = __expf(S[t][3] - mx);
      ls0 += p0 + p1;  ls1 += p2 + p3;
      union { float f; unsigned u; } u0, u1, u2, u3;
      u0.f = p0; u1.f = p1; u2.f = p2; u3.f = p3;
      pw[t * 2]     = ((u0.u + 0x8000u) >> 16) | ((u1.u + 0x8000u) & 0xffff0000u);
      pw[t * 2 + 1] = ((u2.u + 0x8000u) >> 16) | ((u3.u + 0x8000u) & 0xffff0000u);
    }
    float lsum = ls0 + ls1;
    lsum += __shfl_xor(lsum, 16, 64);
    lsum += __shfl_xor(lsum, 32, 64);
    float invd = __builtin_amdgcn_rcpf(lsum);   // every lane: 1/L[row lr]

    f32x4 o[2] = {(f32x4){0.f,0.f,0.f,0.f}, (f32x4){0.f,0.f,0.f,0.f}};
#pragma unroll
    for (int ks = 0; ks < 8; ks++) {
      union { bf16x8 v; unsigned u[4]; } pa;
      pa.u[0] = pw[ks * 4];     pa.u[1] = pw[ks * 4 + 1];
      pa.u[2] = pw[ks * 4 + 2]; pa.u[3] = pw[ks * 4 + 3];
#pragma unroll
      for (int e = 0; e < 2; e++) {
        bf16x8 vb = *(const bf16x8*)(&Vf[(((ks * 2 + e) * 4 + quad) * 16 + lr) * 8]);
        o[e] = __builtin_amdgcn_mfma_f32_16x16x32_bf16(pa.v, vb, o[e], 0, 0, 0);
      }
    }
#pragma unroll
    for (int reg = 0; reg < 4; reg++) {
      float inv = __shfl(invd, quad * 4 + reg, 64);  // L of row i0+4*quad+reg
      int i = i0 + quad * 4 + reg;
      size_t base = ((size_t)r * N + i) * D + h * KD + 2 * lr;
      unsigned gv = *(const unsigned*)(g + base);
      float r0 = o[0][reg] * inv * b2f((u16)(gv & 0xffff));
      float r1 = o[1][reg] * inv * b2f((u16)(gv >> 16));
      *(unsigned*)(og + base) = (unsigned)f2b(r0) | ((unsigned)f2b(r1) << 16);
    }
  }
}

// ---------------- Kernel 3: output projection (async-staged wo) --------------
__global__ __launch_bounds__(256) void out_kernel(
    const u16* __restrict__ og, const u16* __restrict__ wob, const float* __restrict__ bo,
    const float* __restrict__ mask, float* __restrict__ out)
{
  __shared__ __align__(16) u16 Wlds[16384];
  int tid = threadIdx.x;
  async_stage(wob, Wlds, tid);
  int wave = tid >> 6, lane = tid & 63;
  int lr = lane & 15, quad = lane >> 4;
  bf16x8 a[2][4];
#pragma unroll
  for (int mt = 0; mt < 2; mt++) {
    int arow = blockIdx.x * 128 + wave * 32 + mt * 16 + lr;
#pragma unroll
    for (int ks = 0; ks < 4; ks++)
      a[mt][ks] = *(const bf16x8*)(og + (size_t)arow * D + ks * 32 + quad * 8);
  }
  __syncthreads();
  f32x4 acc[2][2][4];
#pragma unroll
  for (int mt = 0; mt < 2; mt++)
#pragma unroll
    for (int tg = 0; tg < 2; tg++)
#pragma unroll
      for (int e = 0; e < 4; e++) acc[mt][tg][e] = (f32x4){0.f, 0.f, 0.f, 0.f};
#pragma unroll
  for (int ks = 0; ks < 4; ks++) {
#pragma unroll
    for (int tg = 0; tg < 2; tg++) {
#pragma unroll
      for (int e = 0; e < 4; e++) {
        int nrow = tg * 64 + 4 * lr + e;
        int gp = (ks * 4 + quad + (nrow & 15)) & 15;
        bf16x8 b = *(const bf16x8*)(&Wlds[nrow * 128 + gp * 8]);
        acc[0][tg][e] = __builtin_amdgcn_mfma_f32_16x16x32_bf16(a[0][ks], b, acc[0][tg][e], 0, 0, 0);
        acc[1][tg][e] = __builtin_amdgcn_mfma_f32_16x16x32_bf16(a[1][ks], b, acc[1][tg][e], 0, 0, 0);
      }
    }
  }
#pragma unroll
  for (int mt = 0; mt < 2; mt++) {
    int row0 = blockIdx.x * 128 + wave * 32 + mt * 16 + quad * 4;
#pragma unroll
    for (int tg = 0; tg < 2; tg++) {
      int c0 = tg * 64 + 4 * lr;
      float4 bo4 = *(const float4*)(bo + c0);
#pragma unroll
      for (int reg = 0; reg < 4; reg++) {
        int pos = row0 + reg;
        float m = mask[pos];
        float4 o4;
        o4.x = (acc[mt][tg][0][reg] + bo4.x) * m;
        o4.y = (acc[mt][tg][1][reg] + bo4.y) * m;
        o4.z = (acc[mt][tg][2][reg] + bo4.z) * m;
        o4.w = (acc[mt][tg][3][reg] + bo4.w) * m;
        *(float4*)(out + (size_t)pos * D + c0) = o4;
      }
    }
  }
}

extern "C" void kernel_launch(void* const* d_in, const int* in_sizes, int n_in,
                              void* d_out, int out_size, void* d_ws, size_t ws_size,
                              hipStream_t stream)
{
  const float* pa   = (const float*)d_in[0];
  const float* mask = (const float*)d_in[1];
  const float* lns  = (const float*)d_in[2];
  const float* lnb  = (const float*)d_in[3];
  const float* w2d  = (const float*)d_in[4];
  const float* wq   = (const float*)d_in[5];
  const float* wk   = (const float*)d_in[6];
  const float* wv   = (const float*)d_in[7];
  const float* wg   = (const float*)d_in[8];
  const float* bg   = (const float*)d_in[9];
  const float* wo   = (const float*)d_in[10];
  const float* bo   = (const float*)d_in[11];

  const size_t ARR = (size_t)NN * D;     // 8M elements
  u16* q  = (u16*)d_ws;
  u16* k  = q + ARR;
  u16* v  = k + ARR;
  u16* g  = v + ARR;
  u16* og = g + ARR;
  float* nb = (float*)(og + ARR);         // NH*NN floats, natural [h][i][j]
  u16* wb = (u16*)(nb + (size_t)NH * NN); // 5*16384 u16, swizzled LDS image

  prep_w_kernel<<<40, 256, 0, stream>>>(wq, wk, wv, wg, wo, wb);
  projln_kernel<<<512, 256, 0, stream>>>(pa, lns, lnb, w2d, wb, bg, q, k, v, g, nb);
  attn_kernel<<<N * NH, 256, 0, stream>>>(q, k, v, g, nb, mask, og);
  out_kernel<<<512, 256, 0, stream>>>(og, wb + 4 * 16384, bo, mask, (float*)d_out);
}

// Round 2
// 238.641 us; speedup vs baseline: 1.3554x; 1.3554x over previous
//
#include <hip/hip_runtime.h>
#include <hip/hip_bf16.h>

typedef unsigned short u16;
typedef __attribute__((ext_vector_type(8))) short bf16x8;
typedef __attribute__((ext_vector_type(4))) float f32x4;
typedef __attribute__((address_space(3))) unsigned lds_u32;
typedef const __attribute__((address_space(1))) unsigned glb_u32;

#define N 256
#define D 128
#define NH 4
#define KD 32
#define NN 65536
#define QK_SCALE 0.17677669529663687f
#define HUGE_MASK 32768.0f

__device__ __forceinline__ float b2f(u16 s) {
  union { float f; unsigned u; } x; x.u = ((unsigned)s) << 16; return x.f;
}
__device__ __forceinline__ u16 f2b(float f) {
  union { float f; unsigned u; } x; x.f = f;
  unsigned r = x.u + 0x7fff + ((x.u >> 16) & 1);
  return (u16)(r >> 16);
}

// ---- Kernel 0: convert 5 weight mats fp32 -> bf16 into the swizzled LDS
// image layout: wb[mat][row*128 + gp*8 + j] = bf16(W[row][g*8+j]),
// gp = (g + (row&15)) & 15. One 8-elem group per thread.
__global__ __launch_bounds__(256) void prep_w_kernel(
    const float* __restrict__ wq, const float* __restrict__ wk,
    const float* __restrict__ wv, const float* __restrict__ wg,
    const float* __restrict__ wo, u16* __restrict__ wb)
{
  int idx = blockIdx.x * 256 + threadIdx.x;          // 0 .. 10239
  const float* srcs[5] = {wq, wk, wv, wg, wo};
  int mat = idx >> 11, rem = idx & 2047;
  int row = rem >> 4, g = rem & 15;
  int gp = (g + (row & 15)) & 15;
  const float* s = srcs[mat] + row * 128 + g * 8;
  float4 f0 = *(const float4*)(s);
  float4 f1 = *(const float4*)(s + 4);
  uint4 pk;
  pk.x = (unsigned)f2b(f0.x) | ((unsigned)f2b(f0.y) << 16);
  pk.y = (unsigned)f2b(f0.z) | ((unsigned)f2b(f0.w) << 16);
  pk.z = (unsigned)f2b(f1.x) | ((unsigned)f2b(f1.y) << 16);
  pk.w = (unsigned)f2b(f1.z) | ((unsigned)f2b(f1.w) << 16);
  *(uint4*)(wb + (size_t)mat * 16384 + row * 128 + gp * 8) = pk;
}

// Async-stage 32 KB (one swizzled weight mat) global -> LDS, width 16.
// LDS dest is wave-uniform base + lane*16 (HW rule), so copy is linear.
__device__ __forceinline__ void async_stage(const u16* __restrict__ gsrc, u16* lds, int tid) {
  int lane = tid & 63, wave = tid >> 6;
  u16* lbase = lds + wave * 512;                 // 1 KB per wave per pass
  const u16* gbase = gsrc + wave * 512 + lane * 8;
#pragma unroll
  for (int p = 0; p < 8; p++) {
    __builtin_amdgcn_global_load_lds((glb_u32*)(gbase + p * 2048),
                                     (lds_u32*)(lbase + p * 2048), 16, 0, 0);
  }
}

// ---------------- Kernel 1: fused LN + nb + q,k,v,g projections --------------
// Grid 512 x 256thr. M=128 rows/block, 2 m-tiles/wave. Weights double-buffered
// via global_load_lds from pre-swizzled wb. nb stored NATURAL order [h][i][j].
__global__ __launch_bounds__(256) void projln_kernel(
    const float* __restrict__ pa, const float* __restrict__ lns, const float* __restrict__ lnb,
    const float* __restrict__ w2d, const u16* __restrict__ wb, const float* __restrict__ bg,
    u16* __restrict__ q, u16* __restrict__ k, u16* __restrict__ v, u16* __restrict__ g,
    float* __restrict__ nb)
{
  __shared__ __align__(16) u16 Wl[2][16384];
  int tid = threadIdx.x;
  int wave = tid >> 6, lane = tid & 63;
  int lr = lane & 15, quad = lane >> 4;

  async_stage(wb, Wl[0], tid);   // mat 0 in flight while LN runs

  bf16x8 a[2][4];
#pragma unroll
  for (int mt = 0; mt < 2; mt++) {
    int row = blockIdx.x * 128 + wave * 32 + mt * 16 + lr;
    const float* rp = pa + (size_t)row * D;
    float xv[4][8];
    float s = 0.f, ss = 0.f;
#pragma unroll
    for (int ks = 0; ks < 4; ks++) {
      float4 a0 = *(const float4*)(rp + ks * 32 + quad * 8);
      float4 a1 = *(const float4*)(rp + ks * 32 + quad * 8 + 4);
      xv[ks][0] = a0.x; xv[ks][1] = a0.y; xv[ks][2] = a0.z; xv[ks][3] = a0.w;
      xv[ks][4] = a1.x; xv[ks][5] = a1.y; xv[ks][6] = a1.z; xv[ks][7] = a1.w;
#pragma unroll
      for (int j = 0; j < 8; j++) { s += xv[ks][j]; ss += xv[ks][j] * xv[ks][j]; }
    }
    s  += __shfl_xor(s, 16, 64);  ss += __shfl_xor(ss, 16, 64);
    s  += __shfl_xor(s, 32, 64);  ss += __shfl_xor(ss, 32, 64);
    float mu = s * (1.0f / D);
    float var = ss * (1.0f / D) - mu * mu;
    float rs = rsqrtf(var + 1e-5f);
#pragma unroll
    for (int ks = 0; ks < 4; ks++) {
      float4 s0 = *(const float4*)(lns + ks * 32 + quad * 8);
      float4 s1 = *(const float4*)(lns + ks * 32 + quad * 8 + 4);
      float4 b0 = *(const float4*)(lnb + ks * 32 + quad * 8);
      float4 b1 = *(const float4*)(lnb + ks * 32 + quad * 8 + 4);
      float sc[8] = {s0.x,s0.y,s0.z,s0.w,s1.x,s1.y,s1.z,s1.w};
      float bi[8] = {b0.x,b0.y,b0.z,b0.w,b1.x,b1.y,b1.z,b1.w};
#pragma unroll
      for (int j = 0; j < 8; j++) xv[ks][j] = (xv[ks][j] - mu) * rs * sc[j] + bi[j];
    }
#pragma unroll
    for (int h = 0; h < NH; h++) {
      float p = 0.f;
#pragma unroll
      for (int ks = 0; ks < 4; ks++) {
        float4 w0 = *(const float4*)(w2d + h * D + ks * 32 + quad * 8);
        float4 w1 = *(const float4*)(w2d + h * D + ks * 32 + quad * 8 + 4);
        p += xv[ks][0]*w0.x + xv[ks][1]*w0.y + xv[ks][2]*w0.z + xv[ks][3]*w0.w
           + xv[ks][4]*w1.x + xv[ks][5]*w1.y + xv[ks][6]*w1.z + xv[ks][7]*w1.w;
      }
      p += __shfl_xor(p, 16, 64);
      p += __shfl_xor(p, 32, 64);
      if (quad == 0)
        nb[(size_t)h * NN + row] = p;   // natural [h][i][j] order, coalesced
    }
#pragma unroll
    for (int ks = 0; ks < 4; ks++)
#pragma unroll
      for (int j = 0; j < 8; j++) a[mt][ks][j] = (short)f2b(xv[ks][j]);
  }
  __syncthreads();   // drains mat-0 global_load_lds (vmcnt) + all waves ready

  u16* Os[4] = {q, k, v, g};
#pragma unroll
  for (int mat = 0; mat < 4; mat++) {
    if (mat < 3) async_stage(wb + (size_t)(mat + 1) * 16384, Wl[(mat + 1) & 1], tid);
    const u16* Wcur = Wl[mat & 1];
    f32x4 acc[2][2][4];
#pragma unroll
    for (int mt = 0; mt < 2; mt++)
#pragma unroll
      for (int tg = 0; tg < 2; tg++)
#pragma unroll
        for (int e = 0; e < 4; e++) acc[mt][tg][e] = (f32x4){0.f, 0.f, 0.f, 0.f};
#pragma unroll
    for (int ks = 0; ks < 4; ks++) {
#pragma unroll
      for (int tg = 0; tg < 2; tg++) {
#pragma unroll
        for (int e = 0; e < 4; e++) {
          int nrow = tg * 64 + 4 * lr + e;
          int gp = (ks * 4 + quad + (nrow & 15)) & 15;
          bf16x8 b = *(const bf16x8*)(&Wcur[nrow * 128 + gp * 8]);
          acc[0][tg][e] = __builtin_amdgcn_mfma_f32_16x16x32_bf16(a[0][ks], b, acc[0][tg][e], 0, 0, 0);
          acc[1][tg][e] = __builtin_amdgcn_mfma_f32_16x16x32_bf16(a[1][ks], b, acc[1][tg][e], 0, 0, 0);
        }
      }
    }
    u16* O = Os[mat];
#pragma unroll
    for (int mt = 0; mt < 2; mt++) {
      int row0 = blockIdx.x * 128 + wave * 32 + mt * 16 + quad * 4;
#pragma unroll
      for (int tg = 0; tg < 2; tg++) {
        int c0 = tg * 64 + 4 * lr;
        float bg0 = 0.f, bg1 = 0.f, bg2 = 0.f, bg3 = 0.f;
        if (mat == 3) { bg0 = bg[c0]; bg1 = bg[c0+1]; bg2 = bg[c0+2]; bg3 = bg[c0+3]; }
#pragma unroll
        for (int reg = 0; reg < 4; reg++) {
          float v0 = acc[mt][tg][0][reg], v1 = acc[mt][tg][1][reg];
          float v2 = acc[mt][tg][2][reg], v3 = acc[mt][tg][3][reg];
          if (mat == 0) { v0 *= QK_SCALE; v1 *= QK_SCALE; v2 *= QK_SCALE; v3 *= QK_SCALE; }
          if (mat == 3) {
            v0 = 1.0f / (1.0f + __expf(-(v0 + bg0)));
            v1 = 1.0f / (1.0f + __expf(-(v1 + bg1)));
            v2 = 1.0f / (1.0f + __expf(-(v2 + bg2)));
            v3 = 1.0f / (1.0f + __expf(-(v3 + bg3)));
          }
          uint2 pk;
          pk.x = (unsigned)f2b(v0) | ((unsigned)f2b(v1) << 16);
          pk.y = (unsigned)f2b(v2) | ((unsigned)f2b(v3) << 16);
          *(uint2*)(O + (size_t)(row0 + reg) * D + c0) = pk;
        }
      }
    }
    __syncthreads();   // next buffer staged (vmcnt drained) + reads done
  }
}

// ---------------- Kernel 2: attention per (r, h) — in-register P path --------
// QK^T computed OPERAND-SWAPPED: S_t = mfma(K_frag, Q_frag) so lane (quad,lr)
// holds S[i = i0+lr][j = 16t + 4*quad + reg]  (one full query row per lane).
// Softmax is per-lane + 2 shfl_xor. P never touches LDS: the lane's own 8
// exp() values per 32-j chunk ARE the PV A-fragment under the k-slot
// permutation pi(8q+jj) = (jj<4 ? 4q+jj : 16+4q+jj-4), which is applied to
// V's LDS staging scatter instead (contraction is permutation-invariant).
// exp/pack is FUSED into the PV loop so S[t] dies as it is consumed:
// no pw[] array -> peak regs ~S(64)+o(8)+misc, no scratch spill
// (round-1 lesson: __launch_bounds__(256,4) forced 64 VGPR -> 470 MB spill).
__global__ __launch_bounds__(256) void attn_kernel(
    const u16* __restrict__ q, const u16* __restrict__ k, const u16* __restrict__ v,
    const u16* __restrict__ g, const float* __restrict__ nb, const float* __restrict__ mask,
    u16* __restrict__ og)
{
  __shared__ __align__(16) u16 Kf[8192];
  __shared__ __align__(16) u16 Vf[8192];
  __shared__ float bias_lds[256];
  int h = blockIdx.x & 3, r = blockIdx.x >> 2;
  int tid = threadIdx.x;
  {
    int j = tid;
    const u16* krow = k + ((size_t)r * N + j) * D + h * KD;
    int t = j >> 4, lrj = j & 15;
#pragma unroll
    for (int qc = 0; qc < 4; qc++)
      *(bf16x8*)(&Kf[((t * 4 + qc) * 16 + lrj) * 8]) = *(const bf16x8*)(krow + qc * 8);
    const u16* vrow = v + ((size_t)r * N + j) * D + h * KD;
    // inverse of pi: source j-rel -> (quad qv, elem jv) slot in the B-fragment
    int ksrc = j >> 5, jrel = j & 31;
    int qv, jv;
    if (jrel < 16) { qv = jrel >> 2; jv = jrel & 3; }
    else           { qv = (jrel & 15) >> 2; jv = 4 + (jrel & 3); }
#pragma unroll
    for (int c = 0; c < 32; c++)
      Vf[(((ksrc * 2 + (c & 1)) * 4 + qv) * 16 + (c >> 1)) * 8 + jv] = vrow[c];
    bias_lds[tid] = HUGE_MASK * (mask[r * N + tid] - 1.0f);
  }
  __syncthreads();
  int wave = tid >> 6, lane = tid & 63;
  int lr = lane & 15, quad = lane >> 4;
  const float* nbh = nb + (size_t)h * NN;

  for (int pass = 0; pass < 4; pass++) {
    int i0 = pass * 64 + wave * 16;
    int irow = i0 + lr;
    bf16x8 af = *(const bf16x8*)(q + ((size_t)r * N + irow) * D + h * KD + quad * 8);
    f32x4 S[16];
#pragma unroll
    for (int t = 0; t < 16; t++) {
      bf16x8 kfr = *(const bf16x8*)(&Kf[((t * 4 + quad) * 16 + lr) * 8]);
      S[t] = __builtin_amdgcn_mfma_f32_16x16x32_bf16(kfr, af, (f32x4){0.f,0.f,0.f,0.f}, 0, 0, 0);
    }
    // add nb[h][irow][j] + mask bias(j); all 64 values belong to row irow
    float mx0 = -3e38f, mx1 = -3e38f, mx2 = -3e38f, mx3 = -3e38f;
    const float* nbrow = nbh + (size_t)irow * N;
#pragma unroll
    for (int t = 0; t < 16; t++) {
      int jb = t * 16 + quad * 4;
      float4 nb4 = *(const float4*)(nbrow + jb);
      float4 b4  = *(const float4*)(&bias_lds[jb]);
      S[t][0] += nb4.x + b4.x;  S[t][1] += nb4.y + b4.y;
      S[t][2] += nb4.z + b4.z;  S[t][3] += nb4.w + b4.w;
      mx0 = fmaxf(mx0, S[t][0]); mx1 = fmaxf(mx1, S[t][1]);
      mx2 = fmaxf(mx2, S[t][2]); mx3 = fmaxf(mx3, S[t][3]);
    }
    float mx = fmaxf(fmaxf(mx0, mx1), fmaxf(mx2, mx3));
    mx = fmaxf(mx, __shfl_xor(mx, 16, 64));   // cross-quad: full row max
    mx = fmaxf(mx, __shfl_xor(mx, 32, 64));

    // Fused exp + pack + PV: S[2ks],S[2ks+1] consumed per iteration.
    float ls = 0.f;
    f32x4 o[2] = {(f32x4){0.f,0.f,0.f,0.f}, (f32x4){0.f,0.f,0.f,0.f}};
#pragma unroll
    for (int ks = 0; ks < 8; ks++) {
      float p0 = __expf(S[2*ks][0] - mx);
      float p1 = __expf(S[2*ks][1] - mx);
      float p2 = __expf(S[2*ks][2] - mx);
      float p3 = __expf(S[2*ks][3] - mx);
      float p4 = __expf(S[2*ks+1][0] - mx);
      float p5 = __expf(S[2*ks+1][1] - mx);
      float p6 = __expf(S[2*ks+1][2] - mx);
      float p7 = __expf(S[2*ks+1][3] - mx);
      ls += ((p0 + p1) + (p2 + p3)) + ((p4 + p5) + (p6 + p7));
      union { bf16x8 v; unsigned u[4]; } pa;
      union { float f; unsigned u; } c0, c1, c2, c3, c4, c5, c6, c7;
      c0.f = p0; c1.f = p1; c2.f = p2; c3.f = p3;
      c4.f = p4; c5.f = p5; c6.f = p6; c7.f = p7;
      pa.u[0] = ((c0.u + 0x8000u) >> 16) | ((c1.u + 0x8000u) & 0xffff0000u);
      pa.u[1] = ((c2.u + 0x8000u) >> 16) | ((c3.u + 0x8000u) & 0xffff0000u);
      pa.u[2] = ((c4.u + 0x8000u) >> 16) | ((c5.u + 0x8000u) & 0xffff0000u);
      pa.u[3] = ((c6.u + 0x8000u) >> 16) | ((c7.u + 0x8000u) & 0xffff0000u);
#pragma unroll
      for (int e = 0; e < 2; e++) {
        bf16x8 vb = *(const bf16x8*)(&Vf[(((ks * 2 + e) * 4 + quad) * 16 + lr) * 8]);
        o[e] = __builtin_amdgcn_mfma_f32_16x16x32_bf16(pa.v, vb, o[e], 0, 0, 0);
      }
    }
    float lsum = ls;
    lsum += __shfl_xor(lsum, 16, 64);
    lsum += __shfl_xor(lsum, 32, 64);
    float invd = __builtin_amdgcn_rcpf(lsum);   // every lane: 1/L[row lr]

#pragma unroll
    for (int reg = 0; reg < 4; reg++) {
      float inv = __shfl(invd, quad * 4 + reg, 64);  // L of row i0+4*quad+reg
      int i = i0 + quad * 4 + reg;
      size_t base = ((size_t)r * N + i) * D + h * KD + 2 * lr;
      unsigned gv = *(const unsigned*)(g + base);
      float r0 = o[0][reg] * inv * b2f((u16)(gv & 0xffff));
      float r1 = o[1][reg] * inv * b2f((u16)(gv >> 16));
      *(unsigned*)(og + base) = (unsigned)f2b(r0) | ((unsigned)f2b(r1) << 16);
    }
  }
}

// ---------------- Kernel 3: output projection (async-staged wo) --------------
__global__ __launch_bounds__(256) void out_kernel(
    const u16* __restrict__ og, const u16* __restrict__ wob, const float* __restrict__ bo,
    const float* __restrict__ mask, float* __restrict__ out)
{
  __shared__ __align__(16) u16 Wlds[16384];
  int tid = threadIdx.x;
  async_stage(wob, Wlds, tid);
  int wave = tid >> 6, lane = tid & 63;
  int lr = lane & 15, quad = lane >> 4;
  bf16x8 a[2][4];
#pragma unroll
  for (int mt = 0; mt < 2; mt++) {
    int arow = blockIdx.x * 128 + wave * 32 + mt * 16 + lr;
#pragma unroll
    for (int ks = 0; ks < 4; ks++)
      a[mt][ks] = *(const bf16x8*)(og + (size_t)arow * D + ks * 32 + quad * 8);
  }
  __syncthreads();
  f32x4 acc[2][2][4];
#pragma unroll
  for (int mt = 0; mt < 2; mt++)
#pragma unroll
    for (int tg = 0; tg < 2; tg++)
#pragma unroll
      for (int e = 0; e < 4; e++) acc[mt][tg][e] = (f32x4){0.f, 0.f, 0.f, 0.f};
#pragma unroll
  for (int ks = 0; ks < 4; ks++) {
#pragma unroll
    for (int tg = 0; tg < 2; tg++) {
#pragma unroll
      for (int e = 0; e < 4; e++) {
        int nrow = tg * 64 + 4 * lr + e;
        int gp = (ks * 4 + quad + (nrow & 15)) & 15;
        bf16x8 b = *(const bf16x8*)(&Wlds[nrow * 128 + gp * 8]);
        acc[0][tg][e] = __builtin_amdgcn_mfma_f32_16x16x32_bf16(a[0][ks], b, acc[0][tg][e], 0, 0, 0);
        acc[1][tg][e] = __builtin_amdgcn_mfma_f32_16x16x32_bf16(a[1][ks], b, acc[1][tg][e], 0, 0, 0);
      }
    }
  }
#pragma unroll
  for (int mt = 0; mt < 2; mt++) {
    int row0 = blockIdx.x * 128 + wave * 32 + mt * 16 + quad * 4;
#pragma unroll
    for (int tg = 0; tg < 2; tg++) {
      int c0 = tg * 64 + 4 * lr;
      float4 bo4 = *(const float4*)(bo + c0);
#pragma unroll
      for (int reg = 0; reg < 4; reg++) {
        int pos = row0 + reg;
        float m = mask[pos];
        float4 o4;
        o4.x = (acc[mt][tg][0][reg] + bo4.x) * m;
        o4.y = (acc[mt][tg][1][reg] + bo4.y) * m;
        o4.z = (acc[mt][tg][2][reg] + bo4.z) * m;
        o4.w = (acc[mt][tg][3][reg] + bo4.w) * m;
        *(float4*)(out + (size_t)pos * D + c0) = o4;
      }
    }
  }
}

extern "C" void kernel_launch(void* const* d_in, const int* in_sizes, int n_in,
                              void* d_out, int out_size, void* d_ws, size_t ws_size,
                              hipStream_t stream)
{
  const float* pa   = (const float*)d_in[0];
  const float* mask = (const float*)d_in[1];
  const float* lns  = (const float*)d_in[2];
  const float* lnb  = (const float*)d_in[3];
  const float* w2d  = (const float*)d_in[4];
  const float* wq   = (const float*)d_in[5];
  const float* wk   = (const float*)d_in[6];
  const float* wv   = (const float*)d_in[7];
  const float* wg   = (const float*)d_in[8];
  const float* bg   = (const float*)d_in[9];
  const float* wo   = (const float*)d_in[10];
  const float* bo   = (const float*)d_in[11];

  const size_t ARR = (size_t)NN * D;     // 8M elements
  u16* q  = (u16*)d_ws;
  u16* k  = q + ARR;
  u16* v  = k + ARR;
  u16* g  = v + ARR;
  u16* og = g + ARR;
  float* nb = (float*)(og + ARR);         // NH*NN floats, natural [h][i][j]
  u16* wb = (u16*)(nb + (size_t)NH * NN); // 5*16384 u16, swizzled LDS image

  prep_w_kernel<<<40, 256, 0, stream>>>(wq, wk, wv, wg, wo, wb);
  projln_kernel<<<512, 256, 0, stream>>>(pa, lns, lnb, w2d, wb, bg, q, k, v, g, nb);
  attn_kernel<<<N * NH, 256, 0, stream>>>(q, k, v, g, nb, mask, og);
  out_kernel<<<512, 256, 0, stream>>>(og, wb + 4 * 16384, bo, mask, (float*)d_out);
}

// Round 4
// 186.744 us; speedup vs baseline: 1.7321x; 1.2779x over previous
//
#include <hip/hip_runtime.h>
#include <hip/hip_bf16.h>

typedef unsigned short u16;
typedef __attribute__((ext_vector_type(8))) short bf16x8;
typedef __attribute__((ext_vector_type(4))) float f32x4;
typedef __attribute__((address_space(3))) unsigned lds_u32;
typedef const __attribute__((address_space(1))) unsigned glb_u32;

#define N 256
#define D 128
#define NH 4
#define KD 32
#define NN 65536
#define QK_SCALE 0.17677669529663687f
#define LOG2E 1.4426950408889634f
#define HUGE_MASK 32768.0f

__device__ __forceinline__ float b2f(u16 s) {
  union { float f; unsigned u; } x; x.u = ((unsigned)s) << 16; return x.f;
}
__device__ __forceinline__ u16 f2b(float f) {
  union { float f; unsigned u; } x; x.f = f;
  unsigned r = x.u + 0x7fff + ((x.u >> 16) & 1);
  return (u16)(r >> 16);
}
// raw v_exp_f32: computes 2^x (used for base-2 softmax; logits pre-scaled by log2e)
__device__ __forceinline__ float exp2v(float x) {
  float r; __asm__("v_exp_f32 %0, %1" : "=v"(r) : "v"(x)); return r;
}

// ---- Kernel 0: convert 5 weight mats fp32 -> bf16 into the swizzled LDS
// image layout: wb[mat][row*128 + gp*8 + j] = bf16(W[row][g*8+j]),
// gp = (g + (row&15)) & 15. One 8-elem group per thread.
__global__ __launch_bounds__(256) void prep_w_kernel(
    const float* __restrict__ wq, const float* __restrict__ wk,
    const float* __restrict__ wv, const float* __restrict__ wg,
    const float* __restrict__ wo, u16* __restrict__ wb)
{
  int idx = blockIdx.x * 256 + threadIdx.x;          // 0 .. 10239
  const float* srcs[5] = {wq, wk, wv, wg, wo};
  int mat = idx >> 11, rem = idx & 2047;
  int row = rem >> 4, g = rem & 15;
  int gp = (g + (row & 15)) & 15;
  const float* s = srcs[mat] + row * 128 + g * 8;
  float4 f0 = *(const float4*)(s);
  float4 f1 = *(const float4*)(s + 4);
  uint4 pk;
  pk.x = (unsigned)f2b(f0.x) | ((unsigned)f2b(f0.y) << 16);
  pk.y = (unsigned)f2b(f0.z) | ((unsigned)f2b(f0.w) << 16);
  pk.z = (unsigned)f2b(f1.x) | ((unsigned)f2b(f1.y) << 16);
  pk.w = (unsigned)f2b(f1.z) | ((unsigned)f2b(f1.w) << 16);
  *(uint4*)(wb + (size_t)mat * 16384 + row * 128 + gp * 8) = pk;
}

// Async-stage 32 KB (one swizzled weight mat) global -> LDS, width 16.
// LDS dest is wave-uniform base + lane*16 (HW rule), so copy is linear.
__device__ __forceinline__ void async_stage(const u16* __restrict__ gsrc, u16* lds, int tid) {
  int lane = tid & 63, wave = tid >> 6;
  u16* lbase = lds + wave * 512;                 // 1 KB per wave per pass
  const u16* gbase = gsrc + wave * 512 + lane * 8;
#pragma unroll
  for (int p = 0; p < 8; p++) {
    __builtin_amdgcn_global_load_lds((glb_u32*)(gbase + p * 2048),
                                     (lds_u32*)(lbase + p * 2048), 16, 0, 0);
  }
}

// ---------------- Kernel 1: fused LN + nb + q,k,v,g projections --------------
// Grid 512 x 256thr. M=128 rows/block, 2 m-tiles/wave. Weights double-buffered
// via global_load_lds from pre-swizzled wb. nb stored NATURAL order [h][i][j],
// PRE-SCALED by log2e (softmax runs in base 2). q is scaled by QK_SCALE*log2e.
__global__ __launch_bounds__(256) void projln_kernel(
    const float* __restrict__ pa, const float* __restrict__ lns, const float* __restrict__ lnb,
    const float* __restrict__ w2d, const u16* __restrict__ wb, const float* __restrict__ bg,
    u16* __restrict__ q, u16* __restrict__ k, u16* __restrict__ v, u16* __restrict__ g,
    float* __restrict__ nb)
{
  __shared__ __align__(16) u16 Wl[2][16384];
  int tid = threadIdx.x;
  int wave = tid >> 6, lane = tid & 63;
  int lr = lane & 15, quad = lane >> 4;

  async_stage(wb, Wl[0], tid);   // mat 0 in flight while LN runs

  bf16x8 a[2][4];
#pragma unroll
  for (int mt = 0; mt < 2; mt++) {
    int row = blockIdx.x * 128 + wave * 32 + mt * 16 + lr;
    const float* rp = pa + (size_t)row * D;
    float xv[4][8];
    float s = 0.f, ss = 0.f;
#pragma unroll
    for (int ks = 0; ks < 4; ks++) {
      float4 a0 = *(const float4*)(rp + ks * 32 + quad * 8);
      float4 a1 = *(const float4*)(rp + ks * 32 + quad * 8 + 4);
      xv[ks][0] = a0.x; xv[ks][1] = a0.y; xv[ks][2] = a0.z; xv[ks][3] = a0.w;
      xv[ks][4] = a1.x; xv[ks][5] = a1.y; xv[ks][6] = a1.z; xv[ks][7] = a1.w;
#pragma unroll
      for (int j = 0; j < 8; j++) { s += xv[ks][j]; ss += xv[ks][j] * xv[ks][j]; }
    }
    s  += __shfl_xor(s, 16, 64);  ss += __shfl_xor(ss, 16, 64);
    s  += __shfl_xor(s, 32, 64);  ss += __shfl_xor(ss, 32, 64);
    float mu = s * (1.0f / D);
    float var = ss * (1.0f / D) - mu * mu;
    float rs = rsqrtf(var + 1e-5f);
#pragma unroll
    for (int ks = 0; ks < 4; ks++) {
      float4 s0 = *(const float4*)(lns + ks * 32 + quad * 8);
      float4 s1 = *(const float4*)(lns + ks * 32 + quad * 8 + 4);
      float4 b0 = *(const float4*)(lnb + ks * 32 + quad * 8);
      float4 b1 = *(const float4*)(lnb + ks * 32 + quad * 8 + 4);
      float sc[8] = {s0.x,s0.y,s0.z,s0.w,s1.x,s1.y,s1.z,s1.w};
      float bi[8] = {b0.x,b0.y,b0.z,b0.w,b1.x,b1.y,b1.z,b1.w};
#pragma unroll
      for (int j = 0; j < 8; j++) xv[ks][j] = (xv[ks][j] - mu) * rs * sc[j] + bi[j];
    }
#pragma unroll
    for (int h = 0; h < NH; h++) {
      float p = 0.f;
#pragma unroll
      for (int ks = 0; ks < 4; ks++) {
        float4 w0 = *(const float4*)(w2d + h * D + ks * 32 + quad * 8);
        float4 w1 = *(const float4*)(w2d + h * D + ks * 32 + quad * 8 + 4);
        p += xv[ks][0]*w0.x + xv[ks][1]*w0.y + xv[ks][2]*w0.z + xv[ks][3]*w0.w
           + xv[ks][4]*w1.x + xv[ks][5]*w1.y + xv[ks][6]*w1.z + xv[ks][7]*w1.w;
      }
      p += __shfl_xor(p, 16, 64);
      p += __shfl_xor(p, 32, 64);
      if (quad == 0)
        nb[(size_t)h * NN + row] = p * LOG2E;   // base-2 domain, coalesced
    }
#pragma unroll
    for (int ks = 0; ks < 4; ks++)
#pragma unroll
      for (int j = 0; j < 8; j++) a[mt][ks][j] = (short)f2b(xv[ks][j]);
  }
  __syncthreads();   // drains mat-0 global_load_lds (vmcnt) + all waves ready

  u16* Os[4] = {q, k, v, g};
#pragma unroll
  for (int mat = 0; mat < 4; mat++) {
    if (mat < 3) async_stage(wb + (size_t)(mat + 1) * 16384, Wl[(mat + 1) & 1], tid);
    const u16* Wcur = Wl[mat & 1];
    f32x4 acc[2][2][4];
#pragma unroll
    for (int mt = 0; mt < 2; mt++)
#pragma unroll
      for (int tg = 0; tg < 2; tg++)
#pragma unroll
        for (int e = 0; e < 4; e++) acc[mt][tg][e] = (f32x4){0.f, 0.f, 0.f, 0.f};
#pragma unroll
    for (int ks = 0; ks < 4; ks++) {
#pragma unroll
      for (int tg = 0; tg < 2; tg++) {
#pragma unroll
        for (int e = 0; e < 4; e++) {
          int nrow = tg * 64 + 4 * lr + e;
          int gp = (ks * 4 + quad + (nrow & 15)) & 15;
          bf16x8 b = *(const bf16x8*)(&Wcur[nrow * 128 + gp * 8]);
          acc[0][tg][e] = __builtin_amdgcn_mfma_f32_16x16x32_bf16(a[0][ks], b, acc[0][tg][e], 0, 0, 0);
          acc[1][tg][e] = __builtin_amdgcn_mfma_f32_16x16x32_bf16(a[1][ks], b, acc[1][tg][e], 0, 0, 0);
        }
      }
    }
    u16* O = Os[mat];
#pragma unroll
    for (int mt = 0; mt < 2; mt++) {
      int row0 = blockIdx.x * 128 + wave * 32 + mt * 16 + quad * 4;
#pragma unroll
      for (int tg = 0; tg < 2; tg++) {
        int c0 = tg * 64 + 4 * lr;
        float bg0 = 0.f, bg1 = 0.f, bg2 = 0.f, bg3 = 0.f;
        if (mat == 3) { bg0 = bg[c0]; bg1 = bg[c0+1]; bg2 = bg[c0+2]; bg3 = bg[c0+3]; }
#pragma unroll
        for (int reg = 0; reg < 4; reg++) {
          float v0 = acc[mt][tg][0][reg], v1 = acc[mt][tg][1][reg];
          float v2 = acc[mt][tg][2][reg], v3 = acc[mt][tg][3][reg];
          if (mat == 0) {
            v0 *= QK_SCALE * LOG2E; v1 *= QK_SCALE * LOG2E;
            v2 *= QK_SCALE * LOG2E; v3 *= QK_SCALE * LOG2E;
          }
          if (mat == 3) {
            v0 = 1.0f / (1.0f + __expf(-(v0 + bg0)));
            v1 = 1.0f / (1.0f + __expf(-(v1 + bg1)));
            v2 = 1.0f / (1.0f + __expf(-(v2 + bg2)));
            v3 = 1.0f / (1.0f + __expf(-(v3 + bg3)));
          }
          uint2 pk;
          pk.x = (unsigned)f2b(v0) | ((unsigned)f2b(v1) << 16);
          pk.y = (unsigned)f2b(v2) | ((unsigned)f2b(v3) << 16);
          *(uint2*)(O + (size_t)(row0 + reg) * D + c0) = pk;
        }
      }
    }
    __syncthreads();   // next buffer staged (vmcnt drained) + reads done
  }
}

// ---------------- Kernel 2: attention per (r, h) — online 2-chunk softmax ----
// Swapped QK^T: lane (quad,lr) holds S[i=i0+lr][j=16t+4*quad+reg].
// nb+bias folded into the MFMA C-operand (C/D layouts identical).
// Online softmax over 2 chunks of 8 tiles halves S register pressure (32 regs).
// Base-2 softmax (inputs pre-scaled by log2e) -> raw v_exp_f32, no mul.
// P packed with v_cvt_pk_bf16_f32 and fed straight to PV MFMA (k-slot
// permutation pi applied to V's staging scatter).
// ROUND-3 BUGFIX: oa/ob element reg belongs to OUTPUT row i0+quad*4+reg
// (C/D layout), not this lane's softmax row lr. The chunk-1 rescale factor
// for that row lives on lane quad*4+reg (whose lr == that row, and m is
// quad-uniform after the cross-quad max reduce) -> fetch via 4 shuffles.
__global__ __launch_bounds__(256) void attn_kernel(
    const u16* __restrict__ q, const u16* __restrict__ k, const u16* __restrict__ v,
    const u16* __restrict__ g, const float* __restrict__ nb, const float* __restrict__ mask,
    u16* __restrict__ og)
{
  __shared__ __align__(16) u16 Kf[8192];
  __shared__ __align__(16) u16 Vf[8192];
  __shared__ float bias_lds[256];
  int h = blockIdx.x & 3, r = blockIdx.x >> 2;
  int tid = threadIdx.x;
  {
    int j = tid;
    const u16* krow = k + ((size_t)r * N + j) * D + h * KD;
    int t = j >> 4, lrj = j & 15;
#pragma unroll
    for (int qc = 0; qc < 4; qc++)
      *(bf16x8*)(&Kf[((t * 4 + qc) * 16 + lrj) * 8]) = *(const bf16x8*)(krow + qc * 8);
    const u16* vrow = v + ((size_t)r * N + j) * D + h * KD;
    // inverse of pi: source j-rel -> (quad qv, elem jv) slot in the B-fragment
    int ksrc = j >> 5, jrel = j & 31;
    int qv, jv;
    if (jrel < 16) { qv = jrel >> 2; jv = jrel & 3; }
    else           { qv = (jrel & 15) >> 2; jv = 4 + (jrel & 3); }
#pragma unroll
    for (int c = 0; c < 32; c++)
      Vf[(((ksrc * 2 + (c & 1)) * 4 + qv) * 16 + (c >> 1)) * 8 + jv] = vrow[c];
    bias_lds[tid] = (HUGE_MASK * LOG2E) * (mask[r * N + tid] - 1.0f);
  }
  __syncthreads();
  int wave = tid >> 6, lane = tid & 63;
  int lr = lane & 15, quad = lane >> 4;
  const float* nbh = nb + (size_t)h * NN;

  for (int pass = 0; pass < 4; pass++) {
    int i0 = pass * 64 + wave * 16;
    int irow = i0 + lr;
    bf16x8 af = *(const bf16x8*)(q + ((size_t)r * N + irow) * D + h * KD + quad * 8);
    const float* nbrow = nbh + (size_t)irow * N;
    float m = 0.f, ls = 0.f;
    f32x4 oa = (f32x4){0.f,0.f,0.f,0.f}, ob = (f32x4){0.f,0.f,0.f,0.f};
#pragma unroll 1
    for (int c = 0; c < 2; c++) {
      f32x4 S[8];
#pragma unroll
      for (int tt = 0; tt < 8; tt++) {
        int t = c * 8 + tt;
        int jb = t * 16 + quad * 4;
        float4 nb4 = *(const float4*)(nbrow + jb);
        float4 b4  = *(const float4*)(&bias_lds[jb]);
        f32x4 ci;
        ci[0] = nb4.x + b4.x; ci[1] = nb4.y + b4.y;
        ci[2] = nb4.z + b4.z; ci[3] = nb4.w + b4.w;
        bf16x8 kfr = *(const bf16x8*)(&Kf[((t * 4 + quad) * 16 + lr) * 8]);
        S[tt] = __builtin_amdgcn_mfma_f32_16x16x32_bf16(kfr, af, ci, 0, 0, 0);
      }
      float m0 = -3e38f, m1 = -3e38f, m2 = -3e38f, m3 = -3e38f;
#pragma unroll
      for (int tt = 0; tt < 8; tt++) {
        m0 = fmaxf(m0, S[tt][0]); m1 = fmaxf(m1, S[tt][1]);
        m2 = fmaxf(m2, S[tt][2]); m3 = fmaxf(m3, S[tt][3]);
      }
      float ma = fmaxf(fmaxf(m0, m1), fmaxf(m2, m3));
      ma = fmaxf(ma, __shfl_xor(ma, 16, 64));   // cross-quad: full row chunk max
      ma = fmaxf(ma, __shfl_xor(ma, 32, 64));
      if (c == 0) {
        m = ma;                                  // first chunk: no rescale
      } else {
        float mnew = fmaxf(m, ma);
        float sc = exp2v(m - mnew);              // row-lr domain
        m = mnew;
        ls *= sc;                                // ls lives in row-lr domain: OK
        // oa/ob[reg] is row i0+quad*4+reg -> need that row's sc (bugfix)
        float s0 = __shfl(sc, quad * 4 + 0, 64);
        float s1 = __shfl(sc, quad * 4 + 1, 64);
        float s2 = __shfl(sc, quad * 4 + 2, 64);
        float s3 = __shfl(sc, quad * 4 + 3, 64);
        oa[0] *= s0; oa[1] *= s1; oa[2] *= s2; oa[3] *= s3;
        ob[0] *= s0; ob[1] *= s1; ob[2] *= s2; ob[3] *= s3;
      }
#pragma unroll
      for (int kk = 0; kk < 4; kk++) {
        int ks = c * 4 + kk;
        float p0 = exp2v(S[2*kk][0] - m);
        float p1 = exp2v(S[2*kk][1] - m);
        float p2 = exp2v(S[2*kk][2] - m);
        float p3 = exp2v(S[2*kk][3] - m);
        float p4 = exp2v(S[2*kk+1][0] - m);
        float p5 = exp2v(S[2*kk+1][1] - m);
        float p6 = exp2v(S[2*kk+1][2] - m);
        float p7 = exp2v(S[2*kk+1][3] - m);
        ls += ((p0 + p1) + (p2 + p3)) + ((p4 + p5) + (p6 + p7));
        union { bf16x8 v; unsigned u[4]; } pa;
        __asm__("v_cvt_pk_bf16_f32 %0, %1, %2" : "=v"(pa.u[0]) : "v"(p0), "v"(p1));
        __asm__("v_cvt_pk_bf16_f32 %0, %1, %2" : "=v"(pa.u[1]) : "v"(p2), "v"(p3));
        __asm__("v_cvt_pk_bf16_f32 %0, %1, %2" : "=v"(pa.u[2]) : "v"(p4), "v"(p5));
        __asm__("v_cvt_pk_bf16_f32 %0, %1, %2" : "=v"(pa.u[3]) : "v"(p6), "v"(p7));
        bf16x8 vb0 = *(const bf16x8*)(&Vf[(((ks * 2 + 0) * 4 + quad) * 16 + lr) * 8]);
        oa = __builtin_amdgcn_mfma_f32_16x16x32_bf16(pa.v, vb0, oa, 0, 0, 0);
        bf16x8 vb1 = *(const bf16x8*)(&Vf[(((ks * 2 + 1) * 4 + quad) * 16 + lr) * 8]);
        ob = __builtin_amdgcn_mfma_f32_16x16x32_bf16(pa.v, vb1, ob, 0, 0, 0);
      }
    }
    float lsum = ls;
    lsum += __shfl_xor(lsum, 16, 64);
    lsum += __shfl_xor(lsum, 32, 64);
    float invd = __builtin_amdgcn_rcpf(lsum);   // every lane: 1/L[row lr]

#pragma unroll
    for (int reg = 0; reg < 4; reg++) {
      float inv = __shfl(invd, quad * 4 + reg, 64);  // L of row i0+4*quad+reg
      int i = i0 + quad * 4 + reg;
      size_t base = ((size_t)r * N + i) * D + h * KD + 2 * lr;
      unsigned gv = *(const unsigned*)(g + base);
      float r0 = oa[reg] * inv * b2f((u16)(gv & 0xffff));
      float r1 = ob[reg] * inv * b2f((u16)(gv >> 16));
      *(unsigned*)(og + base) = (unsigned)f2b(r0) | ((unsigned)f2b(r1) << 16);
    }
  }
}

// ---------------- Kernel 3: output projection (async-staged wo) --------------
__global__ __launch_bounds__(256) void out_kernel(
    const u16* __restrict__ og, const u16* __restrict__ wob, const float* __restrict__ bo,
    const float* __restrict__ mask, float* __restrict__ out)
{
  __shared__ __align__(16) u16 Wlds[16384];
  int tid = threadIdx.x;
  async_stage(wob, Wlds, tid);
  int wave = tid >> 6, lane = tid & 63;
  int lr = lane & 15, quad = lane >> 4;
  bf16x8 a[2][4];
#pragma unroll
  for (int mt = 0; mt < 2; mt++) {
    int arow = blockIdx.x * 128 + wave * 32 + mt * 16 + lr;
#pragma unroll
    for (int ks = 0; ks < 4; ks++)
      a[mt][ks] = *(const bf16x8*)(og + (size_t)arow * D + ks * 32 + quad * 8);
  }
  __syncthreads();
  f32x4 acc[2][2][4];
#pragma unroll
  for (int mt = 0; mt < 2; mt++)
#pragma unroll
    for (int tg = 0; tg < 2; tg++)
#pragma unroll
      for (int e = 0; e < 4; e++) acc[mt][tg][e] = (f32x4){0.f, 0.f, 0.f, 0.f};
#pragma unroll
  for (int ks = 0; ks < 4; ks++) {
#pragma unroll
    for (int tg = 0; tg < 2; tg++) {
#pragma unroll
      for (int e = 0; e < 4; e++) {
        int nrow = tg * 64 + 4 * lr + e;
        int gp = (ks * 4 + quad + (nrow & 15)) & 15;
        bf16x8 b = *(const bf16x8*)(&Wlds[nrow * 128 + gp * 8]);
        acc[0][tg][e] = __builtin_amdgcn_mfma_f32_16x16x32_bf16(a[0][ks], b, acc[0][tg][e], 0, 0, 0);
        acc[1][tg][e] = __builtin_amdgcn_mfma_f32_16x16x32_bf16(a[1][ks], b, acc[1][tg][e], 0, 0, 0);
      }
    }
  }
#pragma unroll
  for (int mt = 0; mt < 2; mt++) {
    int row0 = blockIdx.x * 128 + wave * 32 + mt * 16 + quad * 4;
#pragma unroll
    for (int tg = 0; tg < 2; tg++) {
      int c0 = tg * 64 + 4 * lr;
      float4 bo4 = *(const float4*)(bo + c0);
#pragma unroll
      for (int reg = 0; reg < 4; reg++) {
        int pos = row0 + reg;
        float m = mask[pos];
        float4 o4;
        o4.x = (acc[mt][tg][0][reg] + bo4.x) * m;
        o4.y = (acc[mt][tg][1][reg] + bo4.y) * m;
        o4.z = (acc[mt][tg][2][reg] + bo4.z) * m;
        o4.w = (acc[mt][tg][3][reg] + bo4.w) * m;
        *(float4*)(out + (size_t)pos * D + c0) = o4;
      }
    }
  }
}

extern "C" void kernel_launch(void* const* d_in, const int* in_sizes, int n_in,
                              void* d_out, int out_size, void* d_ws, size_t ws_size,
                              hipStream_t stream)
{
  const float* pa   = (const float*)d_in[0];
  const float* mask = (const float*)d_in[1];
  const float* lns  = (const float*)d_in[2];
  const float* lnb  = (const float*)d_in[3];
  const float* w2d  = (const float*)d_in[4];
  const float* wq   = (const float*)d_in[5];
  const float* wk   = (const float*)d_in[6];
  const float* wv   = (const float*)d_in[7];
  const float* wg   = (const float*)d_in[8];
  const float* bg   = (const float*)d_in[9];
  const float* wo   = (const float*)d_in[10];
  const float* bo   = (const float*)d_in[11];

  const size_t ARR = (size_t)NN * D;     // 8M elements
  u16* q  = (u16*)d_ws;
  u16* k  = q + ARR;
  u16* v  = k + ARR;
  u16* g  = v + ARR;
  u16* og = g + ARR;
  float* nb = (float*)(og + ARR);         // NH*NN floats, natural [h][i][j]
  u16* wb = (u16*)(nb + (size_t)NH * NN); // 5*16384 u16, swizzled LDS image

  prep_w_kernel<<<40, 256, 0, stream>>>(wq, wk, wv, wg, wo, wb);
  projln_kernel<<<512, 256, 0, stream>>>(pa, lns, lnb, w2d, wb, bg, q, k, v, g, nb);
  attn_kernel<<<N * NH, 256, 0, stream>>>(q, k, v, g, nb, mask, og);
  out_kernel<<<512, 256, 0, stream>>>(og, wb + 4 * 16384, bo, mask, (float*)d_out);
}

// Round 5
// 186.571 us; speedup vs baseline: 1.7337x; 1.0009x over previous
//
#include <hip/hip_runtime.h>
#include <hip/hip_bf16.h>

typedef unsigned short u16;
typedef __attribute__((ext_vector_type(8))) short bf16x8;
typedef __attribute__((ext_vector_type(4))) float f32x4;
typedef __attribute__((address_space(3))) unsigned lds_u32;
typedef const __attribute__((address_space(1))) unsigned glb_u32;

#define N 256
#define D 128
#define NH 4
#define KD 32
#define NN 65536
#define QK_SCALE 0.17677669529663687f
#define LOG2E 1.4426950408889634f
#define HUGE_MASK 32768.0f

__device__ __forceinline__ float b2f(u16 s) {
  union { float f; unsigned u; } x; x.u = ((unsigned)s) << 16; return x.f;
}
__device__ __forceinline__ u16 f2b(float f) {
  union { float f; unsigned u; } x; x.f = f;
  unsigned r = x.u + 0x7fff + ((x.u >> 16) & 1);
  return (u16)(r >> 16);
}
// raw v_exp_f32: computes 2^x (used for base-2 softmax; logits pre-scaled by log2e)
__device__ __forceinline__ float exp2v(float x) {
  float r; __asm__("v_exp_f32 %0, %1" : "=v"(r) : "v"(x)); return r;
}

// ---- Kernel 0: convert 5 weight mats fp32 -> bf16 into the swizzled LDS
// image layout: wb[mat][row*128 + gp*8 + j] = bf16(W[row][g*8+j]),
// gp = (g + (row&15)) & 15. One 8-elem group per thread.
__global__ __launch_bounds__(256) void prep_w_kernel(
    const float* __restrict__ wq, const float* __restrict__ wk,
    const float* __restrict__ wv, const float* __restrict__ wg,
    const float* __restrict__ wo, u16* __restrict__ wb)
{
  int idx = blockIdx.x * 256 + threadIdx.x;          // 0 .. 10239
  const float* srcs[5] = {wq, wk, wv, wg, wo};
  int mat = idx >> 11, rem = idx & 2047;
  int row = rem >> 4, g = rem & 15;
  int gp = (g + (row & 15)) & 15;
  const float* s = srcs[mat] + row * 128 + g * 8;
  float4 f0 = *(const float4*)(s);
  float4 f1 = *(const float4*)(s + 4);
  uint4 pk;
  pk.x = (unsigned)f2b(f0.x) | ((unsigned)f2b(f0.y) << 16);
  pk.y = (unsigned)f2b(f0.z) | ((unsigned)f2b(f0.w) << 16);
  pk.z = (unsigned)f2b(f1.x) | ((unsigned)f2b(f1.y) << 16);
  pk.w = (unsigned)f2b(f1.z) | ((unsigned)f2b(f1.w) << 16);
  *(uint4*)(wb + (size_t)mat * 16384 + row * 128 + gp * 8) = pk;
}

// Async-stage 32 KB (one swizzled weight mat) global -> LDS, width 16.
// LDS dest is wave-uniform base + lane*16 (HW rule), so copy is linear.
// NW = number of waves participating; 32 one-KB chunks split among them.
template <int NW>
__device__ __forceinline__ void async_stage(const u16* __restrict__ gsrc, u16* lds, int tid) {
  int lane = tid & 63, wave = tid >> 6;
#pragma unroll
  for (int p = 0; p < 32 / NW; p++) {
    int c = wave * (32 / NW) + p;                // chunk id, 512 u16 each
    __builtin_amdgcn_global_load_lds((glb_u32*)(gsrc + c * 512 + lane * 8),
                                     (lds_u32*)(lds + c * 512), 16, 0, 0);
  }
}

// ---------------- Kernel 1: fused LN + nb + q,k,v,g projections --------------
// Grid 512 x 512thr (8 waves). 128 rows/block, ONE 16-row m-tile per wave
// (round-4 lesson: 256thr/64KB-LDS capped occupancy at 8 waves/CU; 512thr
// doubles it to 16). Weights double-buffered via global_load_lds from
// pre-swizzled wb. nb stored NATURAL [h][i][j], PRE-SCALED by log2e.
__global__ __launch_bounds__(512) void projln_kernel(
    const float* __restrict__ pa, const float* __restrict__ lns, const float* __restrict__ lnb,
    const float* __restrict__ w2d, const u16* __restrict__ wb, const float* __restrict__ bg,
    u16* __restrict__ q, u16* __restrict__ k, u16* __restrict__ v, u16* __restrict__ g,
    float* __restrict__ nb)
{
  __shared__ __align__(16) u16 Wl[2][16384];
  int tid = threadIdx.x;
  int wave = tid >> 6, lane = tid & 63;
  int lr = lane & 15, quad = lane >> 4;

  async_stage<8>(wb, Wl[0], tid);   // mat 0 in flight while LN runs

  bf16x8 a[4];
  int row = blockIdx.x * 128 + wave * 16 + lr;
  {
    const float* rp = pa + (size_t)row * D;
    float xv[4][8];
    float s = 0.f, ss = 0.f;
#pragma unroll
    for (int ks = 0; ks < 4; ks++) {
      float4 a0 = *(const float4*)(rp + ks * 32 + quad * 8);
      float4 a1 = *(const float4*)(rp + ks * 32 + quad * 8 + 4);
      xv[ks][0] = a0.x; xv[ks][1] = a0.y; xv[ks][2] = a0.z; xv[ks][3] = a0.w;
      xv[ks][4] = a1.x; xv[ks][5] = a1.y; xv[ks][6] = a1.z; xv[ks][7] = a1.w;
#pragma unroll
      for (int j = 0; j < 8; j++) { s += xv[ks][j]; ss += xv[ks][j] * xv[ks][j]; }
    }
    s  += __shfl_xor(s, 16, 64);  ss += __shfl_xor(ss, 16, 64);
    s  += __shfl_xor(s, 32, 64);  ss += __shfl_xor(ss, 32, 64);
    float mu = s * (1.0f / D);
    float var = ss * (1.0f / D) - mu * mu;
    float rs = rsqrtf(var + 1e-5f);
#pragma unroll
    for (int ks = 0; ks < 4; ks++) {
      float4 s0 = *(const float4*)(lns + ks * 32 + quad * 8);
      float4 s1 = *(const float4*)(lns + ks * 32 + quad * 8 + 4);
      float4 b0 = *(const float4*)(lnb + ks * 32 + quad * 8);
      float4 b1 = *(const float4*)(lnb + ks * 32 + quad * 8 + 4);
      float sc[8] = {s0.x,s0.y,s0.z,s0.w,s1.x,s1.y,s1.z,s1.w};
      float bi[8] = {b0.x,b0.y,b0.z,b0.w,b1.x,b1.y,b1.z,b1.w};
#pragma unroll
      for (int j = 0; j < 8; j++) xv[ks][j] = (xv[ks][j] - mu) * rs * sc[j] + bi[j];
    }
#pragma unroll
    for (int h = 0; h < NH; h++) {
      float p = 0.f;
#pragma unroll
      for (int ks = 0; ks < 4; ks++) {
        float4 w0 = *(const float4*)(w2d + h * D + ks * 32 + quad * 8);
        float4 w1 = *(const float4*)(w2d + h * D + ks * 32 + quad * 8 + 4);
        p += xv[ks][0]*w0.x + xv[ks][1]*w0.y + xv[ks][2]*w0.z + xv[ks][3]*w0.w
           + xv[ks][4]*w1.x + xv[ks][5]*w1.y + xv[ks][6]*w1.z + xv[ks][7]*w1.w;
      }
      p += __shfl_xor(p, 16, 64);
      p += __shfl_xor(p, 32, 64);
      if (quad == 0)
        nb[(size_t)h * NN + row] = p * LOG2E;   // base-2 domain, coalesced
    }
#pragma unroll
    for (int ks = 0; ks < 4; ks++)
#pragma unroll
      for (int j = 0; j < 8; j++) a[ks][j] = (short)f2b(xv[ks][j]);
  }
  __syncthreads();   // drains mat-0 global_load_lds (vmcnt) + all waves ready

  u16* Os[4] = {q, k, v, g};
#pragma unroll
  for (int mat = 0; mat < 4; mat++) {
    if (mat < 3) async_stage<8>(wb + (size_t)(mat + 1) * 16384, Wl[(mat + 1) & 1], tid);
    const u16* Wcur = Wl[mat & 1];
    f32x4 acc[2][4];
#pragma unroll
    for (int tg = 0; tg < 2; tg++)
#pragma unroll
      for (int e = 0; e < 4; e++) acc[tg][e] = (f32x4){0.f, 0.f, 0.f, 0.f};
#pragma unroll
    for (int ks = 0; ks < 4; ks++) {
#pragma unroll
      for (int tg = 0; tg < 2; tg++) {
#pragma unroll
        for (int e = 0; e < 4; e++) {
          int nrow = tg * 64 + 4 * lr + e;
          int gp = (ks * 4 + quad + (nrow & 15)) & 15;
          bf16x8 b = *(const bf16x8*)(&Wcur[nrow * 128 + gp * 8]);
          acc[tg][e] = __builtin_amdgcn_mfma_f32_16x16x32_bf16(a[ks], b, acc[tg][e], 0, 0, 0);
        }
      }
    }
    u16* O = Os[mat];
    int row0 = blockIdx.x * 128 + wave * 16 + quad * 4;
#pragma unroll
    for (int tg = 0; tg < 2; tg++) {
      int c0 = tg * 64 + 4 * lr;
      float bg0 = 0.f, bg1 = 0.f, bg2 = 0.f, bg3 = 0.f;
      if (mat == 3) { bg0 = bg[c0]; bg1 = bg[c0+1]; bg2 = bg[c0+2]; bg3 = bg[c0+3]; }
#pragma unroll
      for (int reg = 0; reg < 4; reg++) {
        float v0 = acc[tg][0][reg], v1 = acc[tg][1][reg];
        float v2 = acc[tg][2][reg], v3 = acc[tg][3][reg];
        if (mat == 0) {
          v0 *= QK_SCALE * LOG2E; v1 *= QK_SCALE * LOG2E;
          v2 *= QK_SCALE * LOG2E; v3 *= QK_SCALE * LOG2E;
        }
        if (mat == 3) {
          v0 = 1.0f / (1.0f + __expf(-(v0 + bg0)));
          v1 = 1.0f / (1.0f + __expf(-(v1 + bg1)));
          v2 = 1.0f / (1.0f + __expf(-(v2 + bg2)));
          v3 = 1.0f / (1.0f + __expf(-(v3 + bg3)));
        }
        uint2 pk;
        pk.x = (unsigned)f2b(v0) | ((unsigned)f2b(v1) << 16);
        pk.y = (unsigned)f2b(v2) | ((unsigned)f2b(v3) << 16);
        *(uint2*)(O + (size_t)(row0 + reg) * D + c0) = pk;
      }
    }
    __syncthreads();   // next buffer staged (vmcnt drained) + reads done
  }
}

// ---------------- Kernel 2: attention per (r, h) — online 2-chunk softmax ----
// 512 threads (8 waves, 2 passes each): VGPR=52 <= 64 allows 8 waves/SIMD and
// LDS 33KB allows 4 blocks/CU -> occupancy cap 100% (round-4: 256thr capped
// at 16 waves/CU). Swapped QK^T: lane (quad,lr) holds S[i=i0+lr][j=16t+4q+reg].
// nb+bias folded into the MFMA C-operand. Base-2 softmax via raw v_exp_f32.
// P packed with v_cvt_pk_bf16_f32, fed straight to PV MFMA (k-slot
// permutation pi applied to V's staging scatter). Rescale factors for the
// PV accumulator fetched per OUTPUT row via 4 shuffles (round-3 bugfix).
__global__ __launch_bounds__(512) void attn_kernel(
    const u16* __restrict__ q, const u16* __restrict__ k, const u16* __restrict__ v,
    const u16* __restrict__ g, const float* __restrict__ nb, const float* __restrict__ mask,
    u16* __restrict__ og)
{
  __shared__ __align__(16) u16 Kf[8192];
  __shared__ __align__(16) u16 Vf[8192];
  __shared__ float bias_lds[256];
  int h = blockIdx.x & 3, r = blockIdx.x >> 2;
  int tid = threadIdx.x;
  {
    int j = tid & 255;
    if (tid < 256) {
      const u16* krow = k + ((size_t)r * N + j) * D + h * KD;
      int t = j >> 4, lrj = j & 15;
#pragma unroll
      for (int qc = 0; qc < 4; qc++)
        *(bf16x8*)(&Kf[((t * 4 + qc) * 16 + lrj) * 8]) = *(const bf16x8*)(krow + qc * 8);
      bias_lds[j] = (HUGE_MASK * LOG2E) * (mask[r * N + j] - 1.0f);
    }
    // V staging split across all 512 threads: 16 columns each.
    const u16* vrow = v + ((size_t)r * N + j) * D + h * KD;
    // inverse of pi: source j-rel -> (quad qv, elem jv) slot in the B-fragment
    int ksrc = j >> 5, jrel = j & 31;
    int qv, jv;
    if (jrel < 16) { qv = jrel >> 2; jv = jrel & 3; }
    else           { qv = (jrel & 15) >> 2; jv = 4 + (jrel & 3); }
    int chalf = (tid >> 8) * 16;
#pragma unroll
    for (int cc = 0; cc < 16; cc++) {
      int c = chalf + cc;
      Vf[(((ksrc * 2 + (c & 1)) * 4 + qv) * 16 + (c >> 1)) * 8 + jv] = vrow[c];
    }
  }
  __syncthreads();
  int wave = tid >> 6, lane = tid & 63;
  int lr = lane & 15, quad = lane >> 4;
  const float* nbh = nb + (size_t)h * NN;

  for (int pp = 0; pp < 2; pp++) {
    int i0 = pp * 128 + wave * 16;
    int irow = i0 + lr;
    bf16x8 af = *(const bf16x8*)(q + ((size_t)r * N + irow) * D + h * KD + quad * 8);
    const float* nbrow = nbh + (size_t)irow * N;
    float m = 0.f, ls = 0.f;
    f32x4 oa = (f32x4){0.f,0.f,0.f,0.f}, ob = (f32x4){0.f,0.f,0.f,0.f};
#pragma unroll 1
    for (int c = 0; c < 2; c++) {
      f32x4 S[8];
#pragma unroll
      for (int tt = 0; tt < 8; tt++) {
        int t = c * 8 + tt;
        int jb = t * 16 + quad * 4;
        float4 nb4 = *(const float4*)(nbrow + jb);
        float4 b4  = *(const float4*)(&bias_lds[jb]);
        f32x4 ci;
        ci[0] = nb4.x + b4.x; ci[1] = nb4.y + b4.y;
        ci[2] = nb4.z + b4.z; ci[3] = nb4.w + b4.w;
        bf16x8 kfr = *(const bf16x8*)(&Kf[((t * 4 + quad) * 16 + lr) * 8]);
        S[tt] = __builtin_amdgcn_mfma_f32_16x16x32_bf16(kfr, af, ci, 0, 0, 0);
      }
      float m0 = -3e38f, m1 = -3e38f, m2 = -3e38f, m3 = -3e38f;
#pragma unroll
      for (int tt = 0; tt < 8; tt++) {
        m0 = fmaxf(m0, S[tt][0]); m1 = fmaxf(m1, S[tt][1]);
        m2 = fmaxf(m2, S[tt][2]); m3 = fmaxf(m3, S[tt][3]);
      }
      float ma = fmaxf(fmaxf(m0, m1), fmaxf(m2, m3));
      ma = fmaxf(ma, __shfl_xor(ma, 16, 64));   // cross-quad: full row chunk max
      ma = fmaxf(ma, __shfl_xor(ma, 32, 64));
      if (c == 0) {
        m = ma;                                  // first chunk: no rescale
      } else {
        float mnew = fmaxf(m, ma);
        float sc = exp2v(m - mnew);              // row-lr domain
        m = mnew;
        ls *= sc;                                // ls lives in row-lr domain: OK
        // oa/ob[reg] is row i0+quad*4+reg -> need that row's sc
        float s0 = __shfl(sc, quad * 4 + 0, 64);
        float s1 = __shfl(sc, quad * 4 + 1, 64);
        float s2 = __shfl(sc, quad * 4 + 2, 64);
        float s3 = __shfl(sc, quad * 4 + 3, 64);
        oa[0] *= s0; oa[1] *= s1; oa[2] *= s2; oa[3] *= s3;
        ob[0] *= s0; ob[1] *= s1; ob[2] *= s2; ob[3] *= s3;
      }
#pragma unroll
      for (int kk = 0; kk < 4; kk++) {
        int ks = c * 4 + kk;
        float p0 = exp2v(S[2*kk][0] - m);
        float p1 = exp2v(S[2*kk][1] - m);
        float p2 = exp2v(S[2*kk][2] - m);
        float p3 = exp2v(S[2*kk][3] - m);
        float p4 = exp2v(S[2*kk+1][0] - m);
        float p5 = exp2v(S[2*kk+1][1] - m);
        float p6 = exp2v(S[2*kk+1][2] - m);
        float p7 = exp2v(S[2*kk+1][3] - m);
        ls += ((p0 + p1) + (p2 + p3)) + ((p4 + p5) + (p6 + p7));
        union { bf16x8 v; unsigned u[4]; } pa;
        __asm__("v_cvt_pk_bf16_f32 %0, %1, %2" : "=v"(pa.u[0]) : "v"(p0), "v"(p1));
        __asm__("v_cvt_pk_bf16_f32 %0, %1, %2" : "=v"(pa.u[1]) : "v"(p2), "v"(p3));
        __asm__("v_cvt_pk_bf16_f32 %0, %1, %2" : "=v"(pa.u[2]) : "v"(p4), "v"(p5));
        __asm__("v_cvt_pk_bf16_f32 %0, %1, %2" : "=v"(pa.u[3]) : "v"(p6), "v"(p7));
        bf16x8 vb0 = *(const bf16x8*)(&Vf[(((ks * 2 + 0) * 4 + quad) * 16 + lr) * 8]);
        oa = __builtin_amdgcn_mfma_f32_16x16x32_bf16(pa.v, vb0, oa, 0, 0, 0);
        bf16x8 vb1 = *(const bf16x8*)(&Vf[(((ks * 2 + 1) * 4 + quad) * 16 + lr) * 8]);
        ob = __builtin_amdgcn_mfma_f32_16x16x32_bf16(pa.v, vb1, ob, 0, 0, 0);
      }
    }
    float lsum = ls;
    lsum += __shfl_xor(lsum, 16, 64);
    lsum += __shfl_xor(lsum, 32, 64);
    float invd = __builtin_amdgcn_rcpf(lsum);   // every lane: 1/L[row lr]

#pragma unroll
    for (int reg = 0; reg < 4; reg++) {
      float inv = __shfl(invd, quad * 4 + reg, 64);  // L of row i0+4*quad+reg
      int i = i0 + quad * 4 + reg;
      size_t base = ((size_t)r * N + i) * D + h * KD + 2 * lr;
      unsigned gv = *(const unsigned*)(g + base);
      float r0 = oa[reg] * inv * b2f((u16)(gv & 0xffff));
      float r1 = ob[reg] * inv * b2f((u16)(gv >> 16));
      *(unsigned*)(og + base) = (unsigned)f2b(r0) | ((unsigned)f2b(r1) << 16);
    }
  }
}

// ---------------- Kernel 3: output projection (async-staged wo) --------------
// 512 threads (8 waves), 128 rows/block, one 16-row m-tile per wave:
// 32KB LDS x 2 blocks/CU x 8 waves = 16 waves/CU (was 8).
__global__ __launch_bounds__(512) void out_kernel(
    const u16* __restrict__ og, const u16* __restrict__ wob, const float* __restrict__ bo,
    const float* __restrict__ mask, float* __restrict__ out)
{
  __shared__ __align__(16) u16 Wlds[16384];
  int tid = threadIdx.x;
  async_stage<8>(wob, Wlds, tid);
  int wave = tid >> 6, lane = tid & 63;
  int lr = lane & 15, quad = lane >> 4;
  bf16x8 a[4];
  int arow = blockIdx.x * 128 + wave * 16 + lr;
#pragma unroll
  for (int ks = 0; ks < 4; ks++)
    a[ks] = *(const bf16x8*)(og + (size_t)arow * D + ks * 32 + quad * 8);
  __syncthreads();
  f32x4 acc[2][4];
#pragma unroll
  for (int tg = 0; tg < 2; tg++)
#pragma unroll
    for (int e = 0; e < 4; e++) acc[tg][e] = (f32x4){0.f, 0.f, 0.f, 0.f};
#pragma unroll
  for (int ks = 0; ks < 4; ks++) {
#pragma unroll
    for (int tg = 0; tg < 2; tg++) {
#pragma unroll
      for (int e = 0; e < 4; e++) {
        int nrow = tg * 64 + 4 * lr + e;
        int gp = (ks * 4 + quad + (nrow & 15)) & 15;
        bf16x8 b = *(const bf16x8*)(&Wlds[nrow * 128 + gp * 8]);
        acc[tg][e] = __builtin_amdgcn_mfma_f32_16x16x32_bf16(a[ks], b, acc[tg][e], 0, 0, 0);
      }
    }
  }
  int row0 = blockIdx.x * 128 + wave * 16 + quad * 4;
#pragma unroll
  for (int tg = 0; tg < 2; tg++) {
    int c0 = tg * 64 + 4 * lr;
    float4 bo4 = *(const float4*)(bo + c0);
#pragma unroll
    for (int reg = 0; reg < 4; reg++) {
      int pos = row0 + reg;
      float mk = mask[pos];
      float4 o4;
      o4.x = (acc[tg][0][reg] + bo4.x) * mk;
      o4.y = (acc[tg][1][reg] + bo4.y) * mk;
      o4.z = (acc[tg][2][reg] + bo4.z) * mk;
      o4.w = (acc[tg][3][reg] + bo4.w) * mk;
      *(float4*)(out + (size_t)pos * D + c0) = o4;
    }
  }
}

extern "C" void kernel_launch(void* const* d_in, const int* in_sizes, int n_in,
                              void* d_out, int out_size, void* d_ws, size_t ws_size,
                              hipStream_t stream)
{
  const float* pa   = (const float*)d_in[0];
  const float* mask = (const float*)d_in[1];
  const float* lns  = (const float*)d_in[2];
  const float* lnb  = (const float*)d_in[3];
  const float* w2d  = (const float*)d_in[4];
  const float* wq   = (const float*)d_in[5];
  const float* wk   = (const float*)d_in[6];
  const float* wv   = (const float*)d_in[7];
  const float* wg   = (const float*)d_in[8];
  const float* bg   = (const float*)d_in[9];
  const float* wo   = (const float*)d_in[10];
  const float* bo   = (const float*)d_in[11];

  const size_t ARR = (size_t)NN * D;     // 8M elements
  u16* q  = (u16*)d_ws;
  u16* k  = q + ARR;
  u16* v  = k + ARR;
  u16* g  = v + ARR;
  u16* og = g + ARR;
  float* nb = (float*)(og + ARR);         // NH*NN floats, natural [h][i][j]
  u16* wb = (u16*)(nb + (size_t)NH * NN); // 5*16384 u16, swizzled LDS image

  prep_w_kernel<<<40, 256, 0, stream>>>(wq, wk, wv, wg, wo, wb);
  projln_kernel<<<512, 512, 0, stream>>>(pa, lns, lnb, w2d, wb, bg, q, k, v, g, nb);
  attn_kernel<<<N * NH, 512, 0, stream>>>(q, k, v, g, nb, mask, og);
  out_kernel<<<512, 512, 0, stream>>>(og, wb + 4 * 16384, bo, mask, (float*)d_out);
}